// Round 15
// baseline (184.862 us; speedup 1.0000x reference)
//
#include <hip/hip_runtime.h>

typedef _Float16 f16;
typedef _Float16 f16x8 __attribute__((ext_vector_type(8)));
typedef float f32x4 __attribute__((ext_vector_type(4)));

#define K_CODES 8192
#define C_DIM   256
#define N_TOTAL 16384      // 16 * 32 * 32
#define HWSZ    1024

// ---- output layout (floats) ----
#define O_ZQ   0
#define O_LOSS 4194304
#define O_IDX  4194305
#define O_PERP 4210689
#define O_W    4210690
#define O_CS   6307842
#define O_EA   6316034

// ---- workspace layout (float offsets) ----
#define WS_WN    0          // 8192
#define WS_IDX   8192       // 16384 int
#define WS_CNTI  24576      // 8192 int
#define WS_SEG   40960      // 8192 int
#define WS_CUR   49152      // 8192 int
#define WS_PERM  57344      // 16384 int
#define WS_LPART 73728      // 4096
#define WS_NTOT  77824      // 1
#define WS_CAND  81920      // 16384*16 int

#define NQ 8                    // code groups (blockIdx.y) — R9-proven shape
#define QCODES (K_CODES / NQ)   // 1024 codes per group
#define NTILES (QCODES / 32)    // 32 tiles per sweep
#define NCAND  (2 * NQ)         // 16 candidates per row

// ===================== K0: fused prep =====================
// blocks 0..511: z -> -2z f16 hi/lo [row][c]; blocks 512..1535: w -> f16 hi
// + |w|^2; first 8 prepw blocks also zero cnt_i.
__global__ __launch_bounds__(256) void k_prep(const float* __restrict__ z,
                                              const float* __restrict__ w,
                                              f16* __restrict__ zhi,
                                              f16* __restrict__ zlo,
                                              f16* __restrict__ whi,
                                              float* __restrict__ wn,
                                              int* __restrict__ cnt_i)
{
    const int bid = blockIdx.x;
    const int tid = threadIdx.x;
    if (bid < 512) {
        // ---- prepz ----
        __shared__ float zs[32 * C_DIM];   // col XOR-swizzled by ((r>>1)&3)<<2
        const int m0  = bid * 32;
        const int b   = m0 >> 10;
        const int hw0 = m0 & 1023;
        {
            const int i4  = (tid & 7) << 2;
            const int c0s = tid >> 3;
            const float* zp = z + (size_t)b * (C_DIM * HWSZ) + hw0 + i4;
            for (int c = c0s; c < C_DIM; c += 32) {
                float4 v = *(const float4*)(zp + (size_t)c * HWSZ);
                float vv[4] = {v.x, v.y, v.z, v.w};
#pragma unroll
                for (int j = 0; j < 4; ++j) {
                    int r = i4 + j;
                    zs[r * C_DIM + (c ^ (((r >> 1) & 3) << 2))] = vv[j];
                }
            }
        }
        __syncthreads();
        const int r   = tid >> 3;
        const int cc0 = (tid & 7) * 32;
        const int rsw = ((r >> 1) & 3) << 2;
        const size_t obase = (size_t)(m0 + r) * C_DIM + cc0;
#pragma unroll
        for (int p = 0; p < 4; ++p) {
            f16x8 h, l;
#pragma unroll
            for (int e = 0; e < 8; ++e) {
                float v = -2.f * zs[r * C_DIM + ((cc0 + p * 8 + e) ^ rsw)];
                f16 hh = (f16)v;
                h[e] = hh;
                l[e] = (f16)(v - (float)hh);
            }
            *(f16x8*)(zhi + obase + p * 8) = h;
            *(f16x8*)(zlo + obase + p * 8) = l;
        }
    } else {
        // ---- prepw (+ cnt zero) ----
        const int pb = bid - 512;
        if (pb < 8) {
            const int t0 = pb * 1024 + tid * 4;
            *(int4*)&cnt_i[t0] = (int4){0, 0, 0, 0};
        }
        const size_t i8 = ((size_t)pb * 256 + tid) * 8;
        float4 a = *(const float4*)(w + i8);
        float4 b = *(const float4*)(w + i8 + 4);
        float vv[8] = {a.x, a.y, a.z, a.w, b.x, b.y, b.z, b.w};
        f16x8 h;
        float s = 0.f;
#pragma unroll
        for (int e = 0; e < 8; ++e) {
            h[e] = (f16)vv[e];
            s += vv[e] * vv[e];
        }
        *(f16x8*)(whi + i8) = h;
#pragma unroll
        for (int d = 1; d < 32; d <<= 1) s += __shfl_xor(s, d, 64);
        if ((tid & 31) == 0) wn[i8 >> 8] = s;
    }
}

// ===================== K2: MFMA selection — single f16 product ===============
// R12-proven structure; staging switched to global_load_lds width=16 with
// pre-swizzled global source (rule #21: linear LDS dest + inverse-swz SOURCE +
// swz on READ). LDS layout is bit-identical to the reg-staged version:
// LDS[r][c] = g[r][c ^ ((r&7)<<3)] (element units) — read path unchanged.
__global__ __launch_bounds__(512, 4) void k_select(
    const f16* __restrict__ zhi,
    const f16* __restrict__ whi,
    const float* __restrict__ wn, int* __restrict__ cand)
{
    __shared__ f16 wls[2][32 * C_DIM];   // [buf][code*256 + swz k], 16KB/buf

    const int tid  = threadIdx.x;
    const int wave = tid >> 6;
    const int lane = tid & 63;
    const int l15  = lane & 15;
    const int l4   = lane >> 4;

    const int rowbase = blockIdx.x * 256 + wave * 32;
    const int q       = blockIdx.y;
    const int code0   = q * QCODES;

    // ---- A prologue: -2z hi frags resident in regs (64 VGPRs) ----
    f16x8 ah[2][8];
#pragma unroll
    for (int mf = 0; mf < 2; ++mf) {
        const f16* zbh = zhi + (size_t)(rowbase + mf * 16 + l15) * C_DIM + l4 * 8;
#pragma unroll
        for (int ks = 0; ks < 8; ++ks)
            ah[mf][ks] = *(const f16x8*)(zbh + ks * 32);
    }

    // ---- staging precompute: wave stages 2x1KB calls per tile ----
    // call cc: LDS dest = wls[tb] + (cc*8+wave)*512 f16 (wave-uniform, linear)
    // lane: crow = (cc*8+wave)*2 + (lane>>5); global slot = (lane&31)^(crow&7)
    const int pr0   = wave;            // cc=0 pair-row
    const int pr1   = 8 + wave;        // cc=1 pair-row
    const int crow0 = pr0 * 2 + (lane >> 5);
    const int crow1 = pr1 * 2 + (lane >> 5);
    const int gs0   = (lane & 31) ^ (crow0 & 7);   // 16B slot in source row
    const int gs1   = (lane & 31) ^ (crow1 & 7);

    // ---- B-read swizzle bases ----
    const int bsw  = (l15 & 7) << 3;
    const int b_k0 = l4 * 8;

    // ---- packed top-2 state: 8 row-slots (mf*4 + r) ----
    float p1[8], p2[8];
#pragma unroll
    for (int s = 0; s < 8; ++s) { p1[s] = 3.4e38f; p2[s] = 3.4e38f; }

    // ---- stage tile 0 into buf 0 (async; vmcnt drained at loop barrier) ----
    {
        const f16* g0 = whi + (size_t)(code0 + crow0) * C_DIM + gs0 * 8;
        const f16* g1 = whi + (size_t)(code0 + crow1) * C_DIM + gs1 * 8;
        __builtin_amdgcn_global_load_lds(
            (const __attribute__((address_space(1))) void*)g0,
            (__attribute__((address_space(3))) void*)&wls[0][pr0 * 512], 16, 0, 0);
        __builtin_amdgcn_global_load_lds(
            (const __attribute__((address_space(1))) void*)g1,
            (__attribute__((address_space(3))) void*)&wls[0][pr1 * 512], 16, 0, 0);
    }

    for (int t = 0; t < NTILES; ++t) {
        __syncthreads();   // compiler drains vmcnt before s_barrier
        const int buf = t & 1;
        if (t + 1 < NTILES) {   // async-stage next tile into buf^1
            const int cb = code0 + (t + 1) * 32;
            const f16* g0 = whi + (size_t)(cb + crow0) * C_DIM + gs0 * 8;
            const f16* g1 = whi + (size_t)(cb + crow1) * C_DIM + gs1 * 8;
            __builtin_amdgcn_global_load_lds(
                (const __attribute__((address_space(1))) void*)g0,
                (__attribute__((address_space(3))) void*)&wls[buf ^ 1][pr0 * 512], 16, 0, 0);
            __builtin_amdgcn_global_load_lds(
                (const __attribute__((address_space(1))) void*)g1,
                (__attribute__((address_space(3))) void*)&wls[buf ^ 1][pr1 * 512], 16, 0, 0);
        }

        // acc init = wn[code] splat: d = wn - 2 z.w accumulates directly
        const int tbase = t * 32;
        const float wnv0 = wn[code0 + tbase + l15];
        const float wnv1 = wn[code0 + tbase + 16 + l15];
        f32x4 acc[2][2];
#pragma unroll
        for (int mf = 0; mf < 2; ++mf) {
            acc[mf][0] = (f32x4){wnv0, wnv0, wnv0, wnv0};
            acc[mf][1] = (f32x4){wnv1, wnv1, wnv1, wnv1};
        }

#pragma unroll
        for (int ks = 0; ks < 8; ++ks) {
#pragma unroll
            for (int nf = 0; nf < 2; ++nf) {
                const int e = (nf * 16 + l15) * C_DIM + ((ks * 32 + b_k0) ^ bsw);
                f16x8 bh = *(const f16x8*)&wls[buf][e];
#pragma unroll
                for (int mf = 0; mf < 2; ++mf)
                    acc[mf][nf] = __builtin_amdgcn_mfma_f32_16x16x32_f16(ah[mf][ks], bh, acc[mf][nf], 0, 0, 0);
            }
        }

        // ---- packed top-2 update: d = acc (wn already inside) ----
#pragma unroll
        for (int nf = 0; nf < 2; ++nf) {
            const int cl = tbase + nf * 16 + l15;   // code-in-group, 0..1023
#pragma unroll
            for (int mf = 0; mf < 2; ++mf)
#pragma unroll
                for (int r = 0; r < 4; ++r) {
                    const float u = __uint_as_float(
                        (__float_as_uint(acc[mf][nf][r]) & 0xFFFFF800u) | (unsigned)cl);
                    const int s = mf * 4 + r;
                    p2[s] = fminf(p2[s], fmaxf(p1[s], u));   // folds to v_med3
                    p1[s] = fminf(p1[s], u);
                }
        }
    }

    // ---- cross-lane top-2 merge (16-lane groups; lanes own disjoint codes) ----
#pragma unroll
    for (int s = 0; s < 8; ++s) {
        float a1 = p1[s], a2 = p2[s];
#pragma unroll
        for (int st = 1; st <= 8; st <<= 1) {
            float b1 = __shfl_xor(a1, st, 64);
            float b2 = __shfl_xor(a2, st, 64);
            a2 = fminf(fminf(a2, b2), fmaxf(a1, b1));
            a1 = fminf(a1, b1);
        }
        if (l15 == 0) {
            const int row = rowbase + (s >> 2) * 16 + l4 * 4 + (s & 3);
            cand[row * NCAND + q * 2 + 0] = code0 + (int)(__float_as_uint(a1) & 0x7FFu);
            cand[row * NCAND + q * 2 + 1] = code0 + (int)(__float_as_uint(a2) & 0x7FFu);
        }
    }
}

// ===================== K2b: exact rerank + idx outputs + counts ==============
// np-quantized f32 distance: d = fl(fl(a_n + b_k) - fl(2*s_k)),
// a_n = numpy-pairwise(AVX512 order) f32 sum of z^2; s,b from f64; tie->low idx.
__global__ __launch_bounds__(256) void k_rerank(const float* __restrict__ z,
                                                const float* __restrict__ w,
                                                const int* __restrict__ cand,
                                                int* __restrict__ idx,
                                                float* __restrict__ oidx,
                                                int* __restrict__ cnt_i)
{
#pragma clang fp contract(off)
    __shared__ float zs[32 * C_DIM];
    const int tid = threadIdx.x;
    const int m0  = blockIdx.x * 32;
    const int b   = m0 >> 10;
    const int hw0 = m0 & 1023;
    {
        const int i4  = (tid & 7) << 2;
        const int c0s = tid >> 3;
        const float* zp = z + (size_t)b * (C_DIM * HWSZ) + hw0 + i4;
        for (int c = c0s; c < C_DIM; c += 32) {
            float4 v = *(const float4*)(zp + (size_t)c * HWSZ);
            float vv[4] = {v.x, v.y, v.z, v.w};
#pragma unroll
            for (int j = 0; j < 4; ++j) {
                int r = i4 + j;
                zs[r * C_DIM + (c ^ (((r >> 1) & 3) << 2))] = vv[j];
            }
        }
    }
    __syncthreads();

    const int tx  = tid & 15;
    const int ty  = tid >> 4;
    const int zsw = (ty & 3) << 2;

#pragma unroll
    for (int j = 0; j < 2; ++j) {
        const int r   = ty * 2 + j;
        const int row = m0 + r;

        // a_n: numpy pairwise f32 sum of z^2 (AVX512 NPYV order)
        float blk[2];
#pragma unroll
        for (int bb = 0; bb < 2; ++bb) {
            float tarr[8];
#pragma unroll
            for (int t8 = 0; t8 < 8; ++t8) {
                float zz = zs[r * C_DIM + ((bb * 128 + t8 * 16 + tx) ^ zsw)];
                tarr[t8] = zz * zz;
            }
            float p01 = tarr[0] + tarr[1];
            float p23 = tarr[2] + tarr[3];
            float p45 = tarr[4] + tarr[5];
            float p67 = tarr[6] + tarr[7];
            float W = (p01 + p23) + (p45 + p67);
            W += __shfl_xor(W, 8, 64);
            W += __shfl_xor(W, 4, 64);
            W += __shfl_xor(W, 2, 64);
            W += __shfl_xor(W, 1, 64);
            blk[bb] = W;
        }
        const float af = blk[0] + blk[1];

        float bestd = 3.4e38f; int besti = 0x7fffffff;
        for (int c = 0; c < NCAND; ++c) {
            const int ci = cand[row * NCAND + c];
            const float* wp = w + (size_t)ci * C_DIM;
            double ss = 0, qq = 0;
            const int cb = tx * 16;
#pragma unroll
            for (int cc = 0; cc < 16; cc += 4) {
                const int col = cb + cc;
                float4 zv = *(const float4*)&zs[r * C_DIM + (col ^ zsw)];
                float4 wa = *(const float4*)(wp + col);
                ss += (double)zv.x * wa.x + (double)zv.y * wa.y + (double)zv.z * wa.z + (double)zv.w * wa.w;
                qq += (double)wa.x * wa.x + (double)wa.y * wa.y + (double)wa.z * wa.z + (double)wa.w * wa.w;
            }
#pragma unroll
            for (int st = 1; st <= 8; st <<= 1) {
                ss += __shfl_xor(ss, st, 64);
                qq += __shfl_xor(qq, st, 64);
            }
            const float d = (af + (float)qq) - (float)(2.0 * ss);
            if (d < bestd || (d == bestd && ci < besti)) { bestd = d; besti = ci; }
        }
        if (tx == 0) {
            idx[row]  = besti;
            oidx[row] = (float)besti;
            atomicAdd(&cnt_i[besti], 1);
        }
    }
}

// ===================== K3: scan + ntot + perplexity (1 block) ================
__global__ __launch_bounds__(256) void k_scanstats(const int* __restrict__ cnt_i,
                                                   const float* __restrict__ cs,
                                                   int* __restrict__ seg,
                                                   int* __restrict__ cur,
                                                   float* __restrict__ ntot,
                                                   float* __restrict__ out_perp)
{
    __shared__ int ls[256];
    const int tid = threadIdx.x;
    const int base = tid * 32;
    int loc[32];
    int s = 0;
#pragma unroll
    for (int i = 0; i < 32; ++i) { loc[i] = s; s += cnt_i[base + i]; }
    ls[tid] = s;
    __syncthreads();
    for (int off = 1; off < 256; off <<= 1) {
        int v = (tid >= off) ? ls[tid - off] : 0;
        __syncthreads();
        ls[tid] += v;
        __syncthreads();
    }
    const int excl = (tid == 0) ? 0 : ls[tid - 1];
    float sn = 0.f, se = 0.f;
#pragma unroll
    for (int i = 0; i < 32; ++i) {
        const int k = base + i;
        const int cn = cnt_i[k];
        const int o = excl + loc[i];
        seg[k] = o;
        cur[k] = o;
        sn += 0.99f * cs[k] + 0.01f * (float)cn;
        float p = (float)cn * (1.f / (float)N_TOTAL);
        se += p * logf(p + 1e-10f);
    }
#pragma unroll
    for (int d = 1; d < 64; d <<= 1) {
        sn += __shfl_xor(sn, d, 64);
        se += __shfl_xor(se, d, 64);
    }
    __shared__ float r[8];
    if ((tid & 63) == 0) { int wv = tid >> 6; r[wv] = sn; r[4 + wv] = se; }
    __syncthreads();
    if (tid == 0) {
        *ntot = r[0] + r[1] + r[2] + r[3];
        *out_perp = expf(-(r[4] + r[5] + r[6] + r[7]));
    }
}

// ===================== K4: scatter rows into segments (parallel) =============
__global__ __launch_bounds__(256) void k_scatter(const int* __restrict__ idx,
                                                 int* __restrict__ cur,
                                                 int* __restrict__ perm)
{
    const int n = blockIdx.x * 256 + threadIdx.x;
    const int p = atomicAdd(&cur[idx[n]], 1);
    perm[p] = n;
}

// ===================== K5: fused esum + EMA update + normalized weight =======
// Reads zhi/zlo (O_ZQ region) -> MUST run before k_zq overwrites it.
// Writes o_w (overwrites whi — dead after k_select).
__global__ __launch_bounds__(256) void k_update(const f16* __restrict__ zhi,
                                                const f16* __restrict__ zlo,
                                                const int* __restrict__ seg,
                                                const int* __restrict__ cnt_i,
                                                const int* __restrict__ perm,
                                                const float* __restrict__ cs,
                                                const float* __restrict__ ea,
                                                const float* __restrict__ ntot,
                                                float* __restrict__ o_w,
                                                float* __restrict__ o_cs,
                                                float* __restrict__ o_ea)
{
    const int k  = blockIdx.x;
    const int c  = threadIdx.x;
    const int s0 = seg[k];
    const int cn = cnt_i[k];
    float acc = 0.f;
    for (int i = 0; i < cn; ++i) {
        const int n = perm[s0 + i];
        acc += (float)zhi[(size_t)n * C_DIM + c] + (float)zlo[(size_t)n * C_DIM + c];
    }
    const float es = -0.5f * acc;   // zhi+zlo hold -2z
    const float ncs = 0.99f * cs[k] + 0.01f * (float)cn;
    const float n = *ntot;
    const float sm = (ncs + 1e-5f) / (n + (float)K_CODES * 1e-5f) * n;
    if (c == 0) o_cs[k] = ncs;
    const size_t o = (size_t)k * C_DIM + c;
    const float v = 0.99f * ea[o] + 0.01f * es;
    o_ea[o] = v;
    o_w[o]  = v / sm;
}

// ===================== K6: zq gather/STE + loss partials =====================
__global__ __launch_bounds__(256) void k_zq(const float* __restrict__ z,
                                            const float* __restrict__ w,
                                            const int* __restrict__ idx,
                                            float* __restrict__ zq,
                                            float* __restrict__ lpart)
{
    const int bid = blockIdx.x;
    const int b   = bid >> 8;
    const int c   = bid & 255;
    const int tid = threadIdx.x;
    const int hw4 = tid * 4;
    const size_t zoff = (size_t)b * (C_DIM * HWSZ) + (size_t)c * HWSZ + hw4;

    float4 zv = *(const float4*)(z + zoff);
    const int nb = b * HWSZ + hw4;
    int4 iv = *(const int4*)(idx + nb);

    float4 wq;
    wq.x = w[(size_t)iv.x * C_DIM + c];
    wq.y = w[(size_t)iv.y * C_DIM + c];
    wq.z = w[(size_t)iv.z * C_DIM + c];
    wq.w = w[(size_t)iv.w * C_DIM + c];
    *(float4*)(zq + zoff) = wq;

    float dx = wq.x - zv.x, dy = wq.y - zv.y, dz = wq.z - zv.z, dw = wq.w - zv.w;
    float ls = dx * dx + dy * dy + dz * dz + dw * dw;

#pragma unroll
    for (int d = 1; d < 64; d <<= 1) ls += __shfl_xor(ls, d, 64);
    __shared__ float red[4];
    if ((tid & 63) == 0) red[tid >> 6] = ls;
    __syncthreads();
    if (tid == 0) lpart[bid] = red[0] + red[1] + red[2] + red[3];
}

// ===================== K7: loss reduce (1 block) =====================
__global__ __launch_bounds__(256) void k_loss(const float* __restrict__ lpart,
                                              float* __restrict__ out_loss)
{
    const int tid = threadIdx.x;
    float sl = 0.f;
    for (int i = tid; i < 4096; i += 256) sl += lpart[i];
#pragma unroll
    for (int d = 1; d < 64; d <<= 1) sl += __shfl_xor(sl, d, 64);
    __shared__ float r[4];
    if ((tid & 63) == 0) r[tid >> 6] = sl;
    __syncthreads();
    if (tid == 0)
        *out_loss = 0.25f * (r[0] + r[1] + r[2] + r[3]) * (1.f / 4194304.f);
}

// ===================== launch =====================
extern "C" void kernel_launch(void* const* d_in, const int* in_sizes, int n_in,
                              void* d_out, int out_size, void* d_ws, size_t ws_size,
                              hipStream_t stream)
{
    const float* z  = (const float*)d_in[0];
    const float* w  = (const float*)d_in[1];
    const float* cs = (const float*)d_in[2];
    const float* ea = (const float*)d_in[3];
    float* out = (float*)d_out;
    float* ws  = (float*)d_ws;

    float* wn    = ws + WS_WN;
    int*   idx   = (int*)(ws + WS_IDX);
    int*   cnt_i = (int*)(ws + WS_CNTI);
    int*   seg   = (int*)(ws + WS_SEG);
    int*   cur   = (int*)(ws + WS_CUR);
    int*   perm  = (int*)(ws + WS_PERM);
    float* lpart = ws + WS_LPART;
    float* ntot  = ws + WS_NTOT;
    int*   cand  = (int*)(ws + WS_CAND);

    // f16 scratch in out regions overwritten later:
    // zhi/zlo in O_ZQ (read by k_select/k_update, THEN overwritten by k_zq);
    // whi in O_W (+2 floats for 16B align; dead after k_select, overwritten
    // by k_update's o_w store).
    f16* zhi = (f16*)(out + O_ZQ);
    f16* zlo = zhi + (size_t)N_TOTAL * C_DIM;
    f16* whi = (f16*)(out + O_W + 2);

    k_prep     <<<1536, 256, 0, stream>>>(z, w, zhi, zlo, whi, wn, cnt_i);
    k_select   <<<dim3(N_TOTAL / 256, NQ), 512, 0, stream>>>(zhi, whi, wn, cand);
    k_rerank   <<<N_TOTAL / 32, 256, 0, stream>>>(z, w, cand, idx, out + O_IDX, cnt_i);
    k_scanstats<<<1, 256, 0, stream>>>(cnt_i, cs, seg, cur, ntot, out + O_PERP);
    k_scatter  <<<N_TOTAL / 256, 256, 0, stream>>>(idx, cur, perm);
    k_update   <<<K_CODES, 256, 0, stream>>>(zhi, zlo, seg, cnt_i, perm, cs, ea, ntot,
                                             out + O_W, out + O_CS, out + O_EA);
    k_zq       <<<16 * 256, 256, 0, stream>>>(z, w, idx, out + O_ZQ, lpart);
    k_loss     <<<1, 256, 0, stream>>>(lpart, out + O_LOSS);
}

// Round 16
// 182.435 us; speedup vs baseline: 1.0133x; 1.0133x over previous
//
#include <hip/hip_runtime.h>

typedef _Float16 f16;
typedef _Float16 f16x8 __attribute__((ext_vector_type(8)));
typedef float f32x4 __attribute__((ext_vector_type(4)));

#define K_CODES 8192
#define C_DIM   256
#define N_TOTAL 16384      // 16 * 32 * 32
#define HWSZ    1024

// ---- output layout (floats) ----
#define O_ZQ   0
#define O_LOSS 4194304
#define O_IDX  4194305
#define O_PERP 4210689
#define O_W    4210690
#define O_CS   6307842
#define O_EA   6316034

// ---- workspace layout (float offsets) ----
#define WS_WN    0          // 8192
#define WS_IDX   8192       // 16384 int
#define WS_CNTI  24576      // 8192 int
#define WS_SEG   40960      // 8192 int
#define WS_CUR   49152      // 8192 int
#define WS_PERM  57344      // 16384 int
#define WS_LPART 73728      // 4096
#define WS_NTOT  77824      // 1
#define WS_CAND  81920      // 16384*16 int

#define NQ 8                    // code groups (blockIdx.y) — R9-proven shape
#define QCODES (K_CODES / NQ)   // 1024 codes per group
#define NTILES (QCODES / 32)    // 32 tiles per sweep
#define NCAND  (2 * NQ)         // 16 candidates per row

// ===================== K0: fused prep =====================
// blocks 0..511: z -> -2z f16 hi/lo [row][c]; blocks 512..1535: w -> f16 hi
// + |w|^2; first 8 prepw blocks also zero cnt_i.
__global__ __launch_bounds__(256) void k_prep(const float* __restrict__ z,
                                              const float* __restrict__ w,
                                              f16* __restrict__ zhi,
                                              f16* __restrict__ zlo,
                                              f16* __restrict__ whi,
                                              float* __restrict__ wn,
                                              int* __restrict__ cnt_i)
{
    const int bid = blockIdx.x;
    const int tid = threadIdx.x;
    if (bid < 512) {
        // ---- prepz ----
        __shared__ float zs[32 * C_DIM];   // col XOR-swizzled by ((r>>1)&3)<<2
        const int m0  = bid * 32;
        const int b   = m0 >> 10;
        const int hw0 = m0 & 1023;
        {
            const int i4  = (tid & 7) << 2;
            const int c0s = tid >> 3;
            const float* zp = z + (size_t)b * (C_DIM * HWSZ) + hw0 + i4;
            for (int c = c0s; c < C_DIM; c += 32) {
                float4 v = *(const float4*)(zp + (size_t)c * HWSZ);
                float vv[4] = {v.x, v.y, v.z, v.w};
#pragma unroll
                for (int j = 0; j < 4; ++j) {
                    int r = i4 + j;
                    zs[r * C_DIM + (c ^ (((r >> 1) & 3) << 2))] = vv[j];
                }
            }
        }
        __syncthreads();
        const int r   = tid >> 3;
        const int cc0 = (tid & 7) * 32;
        const int rsw = ((r >> 1) & 3) << 2;
        const size_t obase = (size_t)(m0 + r) * C_DIM + cc0;
#pragma unroll
        for (int p = 0; p < 4; ++p) {
            f16x8 h, l;
#pragma unroll
            for (int e = 0; e < 8; ++e) {
                float v = -2.f * zs[r * C_DIM + ((cc0 + p * 8 + e) ^ rsw)];
                f16 hh = (f16)v;
                h[e] = hh;
                l[e] = (f16)(v - (float)hh);
            }
            *(f16x8*)(zhi + obase + p * 8) = h;
            *(f16x8*)(zlo + obase + p * 8) = l;
        }
    } else {
        // ---- prepw (+ cnt zero) ----
        const int pb = bid - 512;
        if (pb < 8) {
            const int t0 = pb * 1024 + tid * 4;
            *(int4*)&cnt_i[t0] = (int4){0, 0, 0, 0};
        }
        const size_t i8 = ((size_t)pb * 256 + tid) * 8;
        float4 a = *(const float4*)(w + i8);
        float4 b = *(const float4*)(w + i8 + 4);
        float vv[8] = {a.x, a.y, a.z, a.w, b.x, b.y, b.z, b.w};
        f16x8 h;
        float s = 0.f;
#pragma unroll
        for (int e = 0; e < 8; ++e) {
            h[e] = (f16)vv[e];
            s += vv[e] * vv[e];
        }
        *(f16x8*)(whi + i8) = h;
#pragma unroll
        for (int d = 1; d < 32; d <<= 1) s += __shfl_xor(s, d, 64);
        if ((tid & 31) == 0) wn[i8 >> 8] = s;
    }
}

// ===================== K2: MFMA selection — single f16 product ===============
// R12-proven body (unchanged): 512 thr / 8 waves; wave = 32 rows (2 Mfrags),
// block = 256 rows x 1024-code group, grid 64 x 8; wn baked into acc init.
// Reg-staged double-buffer (measured faster than global_load_lds here: the
// vmcnt(0)-before-barrier drain exposes async-staging latency, R15).
__global__ __launch_bounds__(512, 4) void k_select(
    const f16* __restrict__ zhi,
    const f16* __restrict__ whi,
    const float* __restrict__ wn, int* __restrict__ cand)
{
    __shared__ f16 wls[2][32 * C_DIM];   // [buf][code*256 + swz k], 16KB/buf

    const int tid  = threadIdx.x;
    const int wave = tid >> 6;
    const int lane = tid & 63;
    const int l15  = lane & 15;
    const int l4   = lane >> 4;

    const int rowbase = blockIdx.x * 256 + wave * 32;
    const int q       = blockIdx.y;
    const int code0   = q * QCODES;

    // ---- A prologue: -2z hi frags resident in regs (64 VGPRs) ----
    f16x8 ah[2][8];
#pragma unroll
    for (int mf = 0; mf < 2; ++mf) {
        const f16* zbh = zhi + (size_t)(rowbase + mf * 16 + l15) * C_DIM + l4 * 8;
#pragma unroll
        for (int ks = 0; ks < 8; ++ks)
            ah[mf][ks] = *(const f16x8*)(zbh + ks * 32);
    }

    // ---- staging: 512 threads x 32B over the 16KB tile ----
    const int s_code = tid >> 4;          // 0..31
    const int s_ch   = tid & 15;          // 0..15
    const int kk0    = s_ch * 8;          // elements 0..120
    const int kk1    = kk0 + 128;
    const int ssw    = (s_code & 7) << 3;
    const int s_lds0 = s_code * C_DIM + (kk0 ^ ssw);
    const int s_lds1 = s_code * C_DIM + (kk1 ^ ssw);

    // ---- B-read swizzle bases ----
    const int bsw  = (l15 & 7) << 3;
    const int b_k0 = l4 * 8;

    // ---- packed top-2 state: 8 row-slots (mf*4 + r) ----
    float p1[8], p2[8];
#pragma unroll
    for (int s = 0; s < 8; ++s) { p1[s] = 3.4e38f; p2[s] = 3.4e38f; }

    // ---- stage tile 0 ----
    {
        const f16* g = whi + (size_t)(code0 + s_code) * C_DIM;
        f16x8 a0 = *(const f16x8*)(g + kk0);
        f16x8 a1 = *(const f16x8*)(g + kk1);
        *(f16x8*)&wls[0][s_lds0] = a0;
        *(f16x8*)&wls[0][s_lds1] = a1;
    }

    for (int t = 0; t < NTILES; ++t) {
        __syncthreads();
        const int buf = t & 1;
        const bool more = (t + 1) < NTILES;
        f16x8 nr0, nr1;
        if (more) {
            const f16* g = whi + (size_t)(code0 + (t + 1) * 32 + s_code) * C_DIM;
            nr0 = *(const f16x8*)(g + kk0);
            nr1 = *(const f16x8*)(g + kk1);
        }

        // acc init = wn[code] splat: d = wn - 2 z.w accumulates directly
        const int tbase = t * 32;
        const float wnv0 = wn[code0 + tbase + l15];
        const float wnv1 = wn[code0 + tbase + 16 + l15];
        f32x4 acc[2][2];
#pragma unroll
        for (int mf = 0; mf < 2; ++mf) {
            acc[mf][0] = (f32x4){wnv0, wnv0, wnv0, wnv0};
            acc[mf][1] = (f32x4){wnv1, wnv1, wnv1, wnv1};
        }

#pragma unroll
        for (int ks = 0; ks < 8; ++ks) {
#pragma unroll
            for (int nf = 0; nf < 2; ++nf) {
                const int e = (nf * 16 + l15) * C_DIM + ((ks * 32 + b_k0) ^ bsw);
                f16x8 bh = *(const f16x8*)&wls[buf][e];
#pragma unroll
                for (int mf = 0; mf < 2; ++mf)
                    acc[mf][nf] = __builtin_amdgcn_mfma_f32_16x16x32_f16(ah[mf][ks], bh, acc[mf][nf], 0, 0, 0);
            }
        }

        // ---- packed top-2 update: d = acc (wn already inside) ----
#pragma unroll
        for (int nf = 0; nf < 2; ++nf) {
            const int cl = tbase + nf * 16 + l15;   // code-in-group, 0..1023
#pragma unroll
            for (int mf = 0; mf < 2; ++mf)
#pragma unroll
                for (int r = 0; r < 4; ++r) {
                    const float u = __uint_as_float(
                        (__float_as_uint(acc[mf][nf][r]) & 0xFFFFF800u) | (unsigned)cl);
                    const int s = mf * 4 + r;
                    p2[s] = fminf(p2[s], fmaxf(p1[s], u));   // folds to v_med3
                    p1[s] = fminf(p1[s], u);
                }
        }

        if (more) {
            *(f16x8*)&wls[buf ^ 1][s_lds0] = nr0;
            *(f16x8*)&wls[buf ^ 1][s_lds1] = nr1;
        }
    }

    // ---- cross-lane top-2 merge (16-lane groups; lanes own disjoint codes) ----
#pragma unroll
    for (int s = 0; s < 8; ++s) {
        float a1 = p1[s], a2 = p2[s];
#pragma unroll
        for (int st = 1; st <= 8; st <<= 1) {
            float b1 = __shfl_xor(a1, st, 64);
            float b2 = __shfl_xor(a2, st, 64);
            a2 = fminf(fminf(a2, b2), fmaxf(a1, b1));
            a1 = fminf(a1, b1);
        }
        if (l15 == 0) {
            const int row = rowbase + (s >> 2) * 16 + l4 * 4 + (s & 3);
            cand[row * NCAND + q * 2 + 0] = code0 + (int)(__float_as_uint(a1) & 0x7FFu);
            cand[row * NCAND + q * 2 + 1] = code0 + (int)(__float_as_uint(a2) & 0x7FFu);
        }
    }
}

// ===================== K2b: exact rerank + idx outputs + counts ==============
// np-quantized f32 distance: d = fl(fl(a_n + b_k) - fl(2*s_k)),
// a_n = numpy-pairwise(AVX512 order) f32 sum of z^2; s,b from f64; tie->low idx.
__global__ __launch_bounds__(256) void k_rerank(const float* __restrict__ z,
                                                const float* __restrict__ w,
                                                const int* __restrict__ cand,
                                                int* __restrict__ idx,
                                                float* __restrict__ oidx,
                                                int* __restrict__ cnt_i)
{
#pragma clang fp contract(off)
    __shared__ float zs[32 * C_DIM];
    const int tid = threadIdx.x;
    const int m0  = blockIdx.x * 32;
    const int b   = m0 >> 10;
    const int hw0 = m0 & 1023;
    {
        const int i4  = (tid & 7) << 2;
        const int c0s = tid >> 3;
        const float* zp = z + (size_t)b * (C_DIM * HWSZ) + hw0 + i4;
        for (int c = c0s; c < C_DIM; c += 32) {
            float4 v = *(const float4*)(zp + (size_t)c * HWSZ);
            float vv[4] = {v.x, v.y, v.z, v.w};
#pragma unroll
            for (int j = 0; j < 4; ++j) {
                int r = i4 + j;
                zs[r * C_DIM + (c ^ (((r >> 1) & 3) << 2))] = vv[j];
            }
        }
    }
    __syncthreads();

    const int tx  = tid & 15;
    const int ty  = tid >> 4;
    const int zsw = (ty & 3) << 2;

#pragma unroll
    for (int j = 0; j < 2; ++j) {
        const int r   = ty * 2 + j;
        const int row = m0 + r;

        // a_n: numpy pairwise f32 sum of z^2 (AVX512 NPYV order)
        float blk[2];
#pragma unroll
        for (int bb = 0; bb < 2; ++bb) {
            float tarr[8];
#pragma unroll
            for (int t8 = 0; t8 < 8; ++t8) {
                float zz = zs[r * C_DIM + ((bb * 128 + t8 * 16 + tx) ^ zsw)];
                tarr[t8] = zz * zz;
            }
            float p01 = tarr[0] + tarr[1];
            float p23 = tarr[2] + tarr[3];
            float p45 = tarr[4] + tarr[5];
            float p67 = tarr[6] + tarr[7];
            float W = (p01 + p23) + (p45 + p67);
            W += __shfl_xor(W, 8, 64);
            W += __shfl_xor(W, 4, 64);
            W += __shfl_xor(W, 2, 64);
            W += __shfl_xor(W, 1, 64);
            blk[bb] = W;
        }
        const float af = blk[0] + blk[1];

        float bestd = 3.4e38f; int besti = 0x7fffffff;
        for (int c = 0; c < NCAND; ++c) {
            const int ci = cand[row * NCAND + c];
            const float* wp = w + (size_t)ci * C_DIM;
            double ss = 0, qq = 0;
            const int cb = tx * 16;
#pragma unroll
            for (int cc = 0; cc < 16; cc += 4) {
                const int col = cb + cc;
                float4 zv = *(const float4*)&zs[r * C_DIM + (col ^ zsw)];
                float4 wa = *(const float4*)(wp + col);
                ss += (double)zv.x * wa.x + (double)zv.y * wa.y + (double)zv.z * wa.z + (double)zv.w * wa.w;
                qq += (double)wa.x * wa.x + (double)wa.y * wa.y + (double)wa.z * wa.z + (double)wa.w * wa.w;
            }
#pragma unroll
            for (int st = 1; st <= 8; st <<= 1) {
                ss += __shfl_xor(ss, st, 64);
                qq += __shfl_xor(qq, st, 64);
            }
            const float d = (af + (float)qq) - (float)(2.0 * ss);
            if (d < bestd || (d == bestd && ci < besti)) { bestd = d; besti = ci; }
        }
        if (tx == 0) {
            idx[row]  = besti;
            oidx[row] = (float)besti;
            atomicAdd(&cnt_i[besti], 1);
        }
    }
}

// ===================== K3: scan + ntot + perplexity (1 block) ================
__global__ __launch_bounds__(256) void k_scanstats(const int* __restrict__ cnt_i,
                                                   const float* __restrict__ cs,
                                                   int* __restrict__ seg,
                                                   int* __restrict__ cur,
                                                   float* __restrict__ ntot,
                                                   float* __restrict__ out_perp)
{
    __shared__ int ls[256];
    const int tid = threadIdx.x;
    const int base = tid * 32;
    int loc[32];
    int s = 0;
#pragma unroll
    for (int i = 0; i < 32; ++i) { loc[i] = s; s += cnt_i[base + i]; }
    ls[tid] = s;
    __syncthreads();
    for (int off = 1; off < 256; off <<= 1) {
        int v = (tid >= off) ? ls[tid - off] : 0;
        __syncthreads();
        ls[tid] += v;
        __syncthreads();
    }
    const int excl = (tid == 0) ? 0 : ls[tid - 1];
    float sn = 0.f, se = 0.f;
#pragma unroll
    for (int i = 0; i < 32; ++i) {
        const int k = base + i;
        const int cn = cnt_i[k];
        const int o = excl + loc[i];
        seg[k] = o;
        cur[k] = o;
        sn += 0.99f * cs[k] + 0.01f * (float)cn;
        float p = (float)cn * (1.f / (float)N_TOTAL);
        se += p * logf(p + 1e-10f);
    }
#pragma unroll
    for (int d = 1; d < 64; d <<= 1) {
        sn += __shfl_xor(sn, d, 64);
        se += __shfl_xor(se, d, 64);
    }
    __shared__ float r[8];
    if ((tid & 63) == 0) { int wv = tid >> 6; r[wv] = sn; r[4 + wv] = se; }
    __syncthreads();
    if (tid == 0) {
        *ntot = r[0] + r[1] + r[2] + r[3];
        *out_perp = expf(-(r[4] + r[5] + r[6] + r[7]));
    }
}

// ===================== K4: scatter rows into segments (parallel) =============
__global__ __launch_bounds__(256) void k_scatter(const int* __restrict__ idx,
                                                 int* __restrict__ cur,
                                                 int* __restrict__ perm)
{
    const int n = blockIdx.x * 256 + threadIdx.x;
    const int p = atomicAdd(&cur[idx[n]], 1);
    perm[p] = n;
}

// ===================== K5: fused esum + EMA update + normalized weight =======
// Reads zhi/zlo (O_ZQ region) -> MUST run before k_zq overwrites it.
// Writes o_w (overwrites whi — dead after k_select).
__global__ __launch_bounds__(256) void k_update(const f16* __restrict__ zhi,
                                                const f16* __restrict__ zlo,
                                                const int* __restrict__ seg,
                                                const int* __restrict__ cnt_i,
                                                const int* __restrict__ perm,
                                                const float* __restrict__ cs,
                                                const float* __restrict__ ea,
                                                const float* __restrict__ ntot,
                                                float* __restrict__ o_w,
                                                float* __restrict__ o_cs,
                                                float* __restrict__ o_ea)
{
    const int k  = blockIdx.x;
    const int c  = threadIdx.x;
    const int s0 = seg[k];
    const int cn = cnt_i[k];
    float acc = 0.f;
    for (int i = 0; i < cn; ++i) {
        const int n = perm[s0 + i];
        acc += (float)zhi[(size_t)n * C_DIM + c] + (float)zlo[(size_t)n * C_DIM + c];
    }
    const float es = -0.5f * acc;   // zhi+zlo hold -2z
    const float ncs = 0.99f * cs[k] + 0.01f * (float)cn;
    const float n = *ntot;
    const float sm = (ncs + 1e-5f) / (n + (float)K_CODES * 1e-5f) * n;
    if (c == 0) o_cs[k] = ncs;
    const size_t o = (size_t)k * C_DIM + c;
    const float v = 0.99f * ea[o] + 0.01f * es;
    o_ea[o] = v;
    o_w[o]  = v / sm;
}

// ===================== K6: zq gather/STE + loss partials =====================
__global__ __launch_bounds__(256) void k_zq(const float* __restrict__ z,
                                            const float* __restrict__ w,
                                            const int* __restrict__ idx,
                                            float* __restrict__ zq,
                                            float* __restrict__ lpart)
{
    const int bid = blockIdx.x;
    const int b   = bid >> 8;
    const int c   = bid & 255;
    const int tid = threadIdx.x;
    const int hw4 = tid * 4;
    const size_t zoff = (size_t)b * (C_DIM * HWSZ) + (size_t)c * HWSZ + hw4;

    float4 zv = *(const float4*)(z + zoff);
    const int nb = b * HWSZ + hw4;
    int4 iv = *(const int4*)(idx + nb);

    float4 wq;
    wq.x = w[(size_t)iv.x * C_DIM + c];
    wq.y = w[(size_t)iv.y * C_DIM + c];
    wq.z = w[(size_t)iv.z * C_DIM + c];
    wq.w = w[(size_t)iv.w * C_DIM + c];
    *(float4*)(zq + zoff) = wq;

    float dx = wq.x - zv.x, dy = wq.y - zv.y, dz = wq.z - zv.z, dw = wq.w - zv.w;
    float ls = dx * dx + dy * dy + dz * dz + dw * dw;

#pragma unroll
    for (int d = 1; d < 64; d <<= 1) ls += __shfl_xor(ls, d, 64);
    __shared__ float red[4];
    if ((tid & 63) == 0) red[tid >> 6] = ls;
    __syncthreads();
    if (tid == 0) lpart[bid] = red[0] + red[1] + red[2] + red[3];
}

// ===================== K7: loss reduce (1 block) =====================
__global__ __launch_bounds__(256) void k_loss(const float* __restrict__ lpart,
                                              float* __restrict__ out_loss)
{
    const int tid = threadIdx.x;
    float sl = 0.f;
    for (int i = tid; i < 4096; i += 256) sl += lpart[i];
#pragma unroll
    for (int d = 1; d < 64; d <<= 1) sl += __shfl_xor(sl, d, 64);
    __shared__ float r[4];
    if ((tid & 63) == 0) r[tid >> 6] = sl;
    __syncthreads();
    if (tid == 0)
        *out_loss = 0.25f * (r[0] + r[1] + r[2] + r[3]) * (1.f / 4194304.f);
}

// ===================== launch =====================
extern "C" void kernel_launch(void* const* d_in, const int* in_sizes, int n_in,
                              void* d_out, int out_size, void* d_ws, size_t ws_size,
                              hipStream_t stream)
{
    const float* z  = (const float*)d_in[0];
    const float* w  = (const float*)d_in[1];
    const float* cs = (const float*)d_in[2];
    const float* ea = (const float*)d_in[3];
    float* out = (float*)d_out;
    float* ws  = (float*)d_ws;

    float* wn    = ws + WS_WN;
    int*   idx   = (int*)(ws + WS_IDX);
    int*   cnt_i = (int*)(ws + WS_CNTI);
    int*   seg   = (int*)(ws + WS_SEG);
    int*   cur   = (int*)(ws + WS_CUR);
    int*   perm  = (int*)(ws + WS_PERM);
    float* lpart = ws + WS_LPART;
    float* ntot  = ws + WS_NTOT;
    int*   cand  = (int*)(ws + WS_CAND);

    // f16 scratch in out regions overwritten later:
    // zhi/zlo in O_ZQ (read by k_select/k_update, THEN overwritten by k_zq);
    // whi in O_W (+2 floats for 16B align; dead after k_select, overwritten
    // by k_update's o_w store).
    f16* zhi = (f16*)(out + O_ZQ);
    f16* zlo = zhi + (size_t)N_TOTAL * C_DIM;
    f16* whi = (f16*)(out + O_W + 2);

    k_prep     <<<1536, 256, 0, stream>>>(z, w, zhi, zlo, whi, wn, cnt_i);
    k_select   <<<dim3(N_TOTAL / 256, NQ), 512, 0, stream>>>(zhi, whi, wn, cand);
    k_rerank   <<<N_TOTAL / 32, 256, 0, stream>>>(z, w, cand, idx, out + O_IDX, cnt_i);
    k_scanstats<<<1, 256, 0, stream>>>(cnt_i, cs, seg, cur, ntot, out + O_PERP);
    k_scatter  <<<N_TOTAL / 256, 256, 0, stream>>>(idx, cur, perm);
    k_update   <<<K_CODES, 256, 0, stream>>>(zhi, zlo, seg, cnt_i, perm, cs, ea, ntot,
                                             out + O_W, out + O_CS, out + O_EA);
    k_zq       <<<16 * 256, 256, 0, stream>>>(z, w, idx, out + O_ZQ, lpart);
    k_loss     <<<1, 256, 0, stream>>>(lpart, out + O_LOSS);
}